// Round 1
// baseline (504.633 us; speedup 1.0000x reference)
//
#include <hip/hip_runtime.h>

// x: [B=4, C=8, H=128, W=128] f32 -> out: [B, C, 210, H*W] f32
// Channels 0..44   : v[j]*v[k],        j<=k       (pairs2, i-major lex order)
// Channels 45..209 : v[i]*(v[j]*v[k]), i<=j<=k    (pairs3, i-major lex order)
//
// R2 restructure: ONE BLOCK PER (plane, channel). Each block writes its 64 KB
// channel-plane CONTIGUOUSLY (4 KB per iteration), recomputing the 2-3 taps it
// needs from the L2-resident 64 KB input plane via unaligned float4 loads.
//
// Rationale (R1 post-mortem): the previous mapping gave each thread all 210
// channels of 4 pixels -> every store address congruent mod 64 KB (channel
// stride = 2^16 B). Per-wave 105 KB bursts hammered one 1 KB slice of the
// 64 KB period (same few L2 sets / HBM granules), and the 110-deep unrolled
// store burst risked VGPR spills. Measured 1.02 TB/s vs ~4.5-6 TB/s write
// ceiling. This layout makes the store stream memset-shaped.

#define HH 128
#define WW 128
#define LL (HH * WW)
#define NCH 210

__device__ __forceinline__ constexpr int tri9(int m) { return m * (m + 1) / 2; }

// Load the sliding-window float4 for tap (dh, dw) at output rows h, cols
// [w0, w0+3]. Window = x[h+dh-1][w0+dw-1 .. w0+dw+2], zero-padded outside.
// dh/dw are block-uniform; wq tests are per-lane (exec-masked, cheap).
template <bool EDGE>
__device__ __forceinline__ float4 load_tap(const float* __restrict__ xp,
                                           int h, int dh, int dw,
                                           int wq, int w0) {
    const int row = h + dh - 1;
    int off = row * WW + w0 + dw - 1;
    // Lane-edge address fixups so the 16B load stays inside the row; the
    // loaded values are shifted into window position below.
    if (dw == 0) off += (wq == 0) ? 1 : 0;    // would read x[row][-1]
    if (dw == 2) off -= (wq == 31) ? 1 : 0;   // would read x[row][128]
    if (EDGE) {
        // row may be -1 or 128 here; clamp address into the plane (values
        // are zeroed afterwards), avoids OOB access on first/last plane.
        off = off < 0 ? 0 : off;
        off = off > (LL - 4) ? (LL - 4) : off;
    }
    float4 v = *reinterpret_cast<const float4*>(xp + off);
    if (dw == 0) {
        if (wq == 0)  { v.w = v.z; v.z = v.y; v.y = v.x; v.x = 0.f; }
    }
    if (dw == 2) {
        if (wq == 31) { v.x = v.y; v.y = v.z; v.z = v.w; v.w = 0.f; }
    }
    if (EDGE) {
        if ((unsigned)row >= (unsigned)HH) { v.x = 0.f; v.y = 0.f; v.z = 0.f; v.w = 0.f; }
    }
    return v;
}

template <bool EDGE>
__device__ __forceinline__ void do_row(const float* __restrict__ xp,
                                       float* __restrict__ op,
                                       int h, int wq, int w0,
                                       int dhA, int dwA, int dhB, int dwB,
                                       int dhC, int dwC, bool o3) {
    // FP order must match reference exactly: t = v[j]*v[k]; out3 = v[i]*t.
    float4 vb = load_tap<EDGE>(xp, h, dhB, dwB, wq, w0);
    float4 vc = load_tap<EDGE>(xp, h, dhC, dwC, wq, w0);
    float4 t;
    t.x = vb.x * vc.x;
    t.y = vb.y * vc.y;
    t.z = vb.z * vc.z;
    t.w = vb.w * vc.w;
    if (o3) {  // block-uniform branch
        float4 va = load_tap<EDGE>(xp, h, dhA, dwA, wq, w0);
        t.x = va.x * t.x;
        t.y = va.y * t.y;
        t.z = va.z * t.z;
        t.w = va.w * t.w;
    }
    *reinterpret_cast<float4*>(op + h * WW + w0) = t;
}

__global__ __launch_bounds__(256, 4) void hoi_kernel(const float* __restrict__ x,
                                                     float* __restrict__ out) {
    const int ch    = blockIdx.x;   // 0..209
    const int plane = blockIdx.y;   // 0..31 (b*C + c)

    // Decode channel -> tap indices (block-uniform scalar loops).
    int A = 0, Bt = 0, Ct = 0;
    bool o3;
    {
        int c = ch;
        if (c < 45) {
            o3 = false;
            int j = 0;
            while (c >= 9 - j) { c -= 9 - j; ++j; }
            Bt = j; Ct = j + c;                 // out = v[Bt] * v[Ct]
        } else {
            o3 = true;
            c -= 45;
            int i = 0;
            while (c >= tri9(9 - i)) { c -= tri9(9 - i); ++i; }
            int j = i;
            while (c >= 9 - j) { c -= 9 - j; ++j; }
            A = i; Bt = j; Ct = j + c;          // out = v[A] * (v[Bt] * v[Ct])
        }
    }
    const int dhA = A / 3,  dwA = A % 3;
    const int dhB = Bt / 3, dwB = Bt % 3;
    const int dhC = Ct / 3, dwC = Ct % 3;

    const int tid = threadIdx.x;
    const int wq  = tid & 31;        // 32 column-quads cover the 128-wide row
    const int w0  = wq << 2;
    const int hs  = tid >> 5;        // 0..7 row sub-index

    const float* __restrict__ xp = x + (size_t)plane * LL;
    float* __restrict__ op = out + ((size_t)plane * NCH + ch) * LL;

    // 16 iterations; iteration `it` writes rows it*8 .. it*8+7 = 4 KB
    // contiguous per block. Only it==0 / it==15 can touch padded rows.
    do_row<true>(xp, op, 0 * 8 + hs, wq, w0, dhA, dwA, dhB, dwB, dhC, dwC, o3);
#pragma unroll
    for (int it = 1; it < 15; ++it)
        do_row<false>(xp, op, it * 8 + hs, wq, w0, dhA, dwA, dhB, dwB, dhC, dwC, o3);
    do_row<true>(xp, op, 15 * 8 + hs, wq, w0, dhA, dwA, dhB, dwB, dhC, dwC, o3);
}

extern "C" void kernel_launch(void* const* d_in, const int* in_sizes, int n_in,
                              void* d_out, int out_size, void* d_ws, size_t ws_size,
                              hipStream_t stream) {
    const float* x = (const float*)d_in[0];
    float* out = (float*)d_out;

    const int nplanes = in_sizes[0] / LL;   // B*C = 32 (element count, as verified in R1)
    hoi_kernel<<<dim3(NCH, nplanes), 256, 0, stream>>>(x, out);
}